// Round 14
// baseline (3609.377 us; speedup 1.0000x reference)
//
#include <hip/hip_runtime.h>
#include <hip/hip_bf16.h>
#include <cstdint>

#define T_ 512
#define B_ 1024
#define D_ 6
#define H_ 128
#define CH_ 8   // chunk timesteps in lstm kernels
#define CT_ 16  // timesteps per conv block
#define NP_ 256 // producer block count

typedef _Float16 f16;
typedef _Float16 f16x8 __attribute__((ext_vector_type(8)));
typedef float f32x4 __attribute__((ext_vector_type(4)));

// branch-free erf (Abramowitz-Stegun 7.1.26, max abs err 1.5e-7)
__device__ __forceinline__ float erf_f(float x) {
    float ax = fabsf(x);
    float t = __builtin_amdgcn_rcpf(fmaf(0.3275911f, ax, 1.f));
    float p = fmaf(t, 1.061405429f, -1.453152027f);
    p = fmaf(t, p, 1.421413741f);
    p = fmaf(t, p, -0.284496736f);
    p = fmaf(t, p, 0.254829592f);
    p = p * t;
    float e = __builtin_amdgcn_exp2f(-ax * ax * 1.4426950408889634f);
    float r = 1.f - p * e;
    return copysignf(r, x);
}
__device__ __forceinline__ float gelu_f(float x) {
    return 0.5f * x * (1.f + erf_f(x * 0.7071067811865476f));
}
__device__ __forceinline__ float sig_f(float x) {
    return __builtin_amdgcn_rcpf(1.f + __builtin_amdgcn_exp2f(-1.4426950408889634f * x));
}
__device__ __forceinline__ float tanh_f(float x) {
    return 2.f * sig_f(2.f * x) - 1.f;
}
__device__ __forceinline__ f16x8 load8cvt(const float* p) {
    float4 a = ((const float4*)p)[0];
    float4 b = ((const float4*)p)[1];
    f16x8 r = { (f16)a.x, (f16)a.y, (f16)a.z, (f16)a.w,
                (f16)b.x, (f16)b.y, (f16)b.z, (f16)b.w };
    return r;
}
// LDS tiles: row-major [rows][128] f16, 256B row stride, 16B-chunk XOR swizzle
__device__ __forceinline__ f16x8 lds_rd8(const f16* base, int row, int cb) {
    const char* p = (const char*)base + row * 256 + (cb ^ ((row & 7) << 4));
    return *(const f16x8*)p;
}
__device__ __forceinline__ void lds_wr1(f16* base, int row, int col, f16 v) {
    char* p = (char*)base + row * 256 + ((col * 2) ^ ((row & 7) << 4));
    *(f16*)p = v;
}
// ZX tile: [32 rows][512 cols] f16, 1024B row stride, same XOR swizzle
__device__ __forceinline__ void zx_wr(f16* base, int row, int col, f16 v) {
    char* p = (char*)base + row * 1024 + ((col * 2) ^ ((row & 7) << 4));
    *(f16*)p = v;
}
__device__ __forceinline__ float zx_rd(const f16* base, int row, int col) {
    const char* p = (const char*)base + row * 1024 + ((col * 2) ^ ((row & 7) << 4));
    return (float)*(const f16*)p;
}

// ---------------------------------------------------------------------------
// K1: conv stack STANDALONE (R13-proven, ~144us). 8192 blocks x 512 thr.
// ---------------------------------------------------------------------------
__global__ __launch_bounds__(512) void conv_k(
    const float* __restrict__ src,
    const float* __restrict__ w0p, const float* __restrict__ b0p,
    const float* __restrict__ w1p, const float* __restrict__ b1p,
    const float* __restrict__ w2p, const float* __restrict__ b2p,
    const float* __restrict__ w3p, const float* __restrict__ b3p,
    const float* __restrict__ posp, f16* __restrict__ xout)
{
    __shared__ f16 XA0[64 * 128];   // 16KB
    __shared__ f16 XA1[64 * 128];   // 16KB
    const int tid = threadIdx.x;
    const int lane = tid & 63, wid = tid >> 6;
    const int l16 = lane & 15, hi = lane >> 4;
    const int t0 = (blockIdx.x & 31) * CT_;
    const int bb0 = (blockIdx.x >> 5) * 4;
    const int mycol = wid * 16 + l16;

    f16x8 cw[3][4];
    {
        const float* wp[3] = { w1p, w2p, w3p };
#pragma unroll
        for (int L = 0; L < 3; ++L)
#pragma unroll
            for (int ki = 0; ki < 4; ++ki)
                cw[L][ki] = load8cvt(wp[L] + mycol * 128 + ki * 32 + hi * 8);
    }
    const int col0 = tid & 127;
    const int r0 = tid >> 7;
    float w0c[6], b0c;
#pragma unroll
    for (int k = 0; k < 6; ++k) w0c[k] = w0p[col0 * 6 + k];
    b0c = b0p[col0];
    const float b1c = b1p[mycol], b2c = b2p[mycol], b3c = b3p[mycol];

    {
        const float2* sp0 = (const float2*)src + ((size_t)(bb0 + r0) * T_ + t0) * 3;
#pragma unroll
        for (int it = 0; it < CT_; ++it) {
            float2 a = sp0[it * 3 + 0], b = sp0[it * 3 + 1], c2 = sp0[it * 3 + 2];
            float acc = b0c;
            acc = fmaf(a.x, w0c[0], acc);
            acc = fmaf(a.y, w0c[1], acc);
            acc = fmaf(b.x, w0c[2], acc);
            acc = fmaf(b.y, w0c[3], acc);
            acc = fmaf(c2.x, w0c[4], acc);
            acc = fmaf(c2.y, w0c[5], acc);
            lds_wr1(XA0, it * 4 + r0, col0, (f16)gelu_f(acc));
        }
    }
    __syncthreads();

    auto conv_mfma = [&](const f16* Xin, f16* Xout, int L, float bc, bool addpos) {
#pragma unroll
        for (int mt = 0; mt < 4; ++mt) {
            f16x8 af[4];
#pragma unroll
            for (int ki = 0; ki < 4; ++ki)
                af[ki] = lds_rd8(Xin, mt * 16 + l16, ki * 64 + hi * 16);
            f32x4 acc = { bc, bc, bc, bc };
#pragma unroll
            for (int ki = 0; ki < 4; ++ki)
                acc = __builtin_amdgcn_mfma_f32_16x16x32_f16(af[ki], cw[L][ki], acc, 0, 0, 0);
            float pv = 0.f;
            if (addpos) pv = posp[(t0 + mt * 4 + hi) * 128 + mycol];
#pragma unroll
            for (int j = 0; j < 4; ++j)
                lds_wr1(Xout, mt * 16 + hi * 4 + j, mycol, (f16)(gelu_f(acc[j]) + pv));
        }
    };
    conv_mfma(XA0, XA1, 0, b1c, false);
    __syncthreads();
    conv_mfma(XA1, XA0, 1, b2c, false);
    __syncthreads();
    conv_mfma(XA0, XA1, 2, b3c, true);   // + pos_embed
    __syncthreads();

#pragma unroll
    for (int pass = 0; pass < 2; ++pass) {
        int u = pass * 512 + tid;
        int tau = u >> 4, cw8 = u & 15;
        f16x8 v = lds_rd8(XA1, tau, cw8 * 16);
        *(f16x8*)(xout + (size_t)(t0 + (tau >> 2)) * (B_ * H_) +
                  (size_t)(bb0 + (tau & 3)) * H_ + cw8 * 8) = v;
    }
}

// ---------------------------------------------------------------------------
// K2: producer/consumer LSTM — both layers overlapped in ONE launch.
// 512 blocks x 512 thr; blocks 0..255 = lstm0 (producer p, batch rows 4p),
// blocks 256..511 = lstm1 (consumer p). Each path = the R13-proven
// lstm_chunk structure (one resident whh, 64 frag regs, <=128 VGPR,
// LDS prod 42KB / cons 34KB -> 2 blocks/CU co-residency target).
// Producer per chunk: zgemm0 | 8 slots -> YH | flush ys | fence | flag (rel).
// Consumer per chunk: spin flag (acq) | zgemm1 (A from global ys) | 8 slots.
// Cross-XCD safety: agent-scope release/acquire (R11-proven correct).
// Producers never wait on consumers -> no deadlock mode; worst case = serial.
// ---------------------------------------------------------------------------
__global__ __launch_bounds__(512) void lstm_pc_k(
    const f16* __restrict__ xb,
    const float* __restrict__ Wih0, const float* __restrict__ Whh0,
    const float* __restrict__ bih0, const float* __restrict__ bhh0,
    const float* __restrict__ Wih1, const float* __restrict__ Whh1,
    const float* __restrict__ bih1, const float* __restrict__ bhh1,
    f16* __restrict__ ys, int* __restrict__ flags,
    float* __restrict__ hfin)
{
    __shared__ f16 ZX[32 * 512];          // 32KB (both paths)
    __shared__ f16 YH[32 * 128];          // 8KB (producer only)
    __shared__ f16 HL[2][4 * 128];        // 2KB

    const int tid = threadIdx.x;
    const int lane = tid & 63, wid = tid >> 6;
    const int l16 = lane & 15, hi = lane >> 4;
    const bool producer = (int)blockIdx.x < NP_;
    const int p = producer ? (int)blockIdx.x : (int)blockIdx.x - NP_;
    const int bb0 = p * 4;
    const int mycol = wid * 16 + l16;

    const float* Wih = producer ? Wih0 : Wih1;
    const float* Whh = producer ? Whh0 : Whh1;
    const float* bih = producer ? bih0 : bih1;
    const float* bhh = producer ? bhh0 : bhh1;

    f16x8 whh[4][4];
    float biasg[4];
#pragma unroll
    for (int g = 0; g < 4; ++g) {
        int n = g * 128 + mycol;
        biasg[g] = bih[n] + bhh[n];
#pragma unroll
        for (int ki = 0; ki < 4; ++ki)
            whh[g][ki] = load8cvt(Whh + n * 128 + ki * 32 + hi * 8);
    }
    for (int i = tid; i < 2 * 4 * 128; i += 512) ((f16*)HL)[i] = (f16)0.f;

    float c = 0.f, h = 0.f;
    __syncthreads();

    auto zgemm = [&](const f16* Asrc /*global chunk base for bb0*/, int t0) {
        f16x8 af[2][4];
#pragma unroll
        for (int mt = 0; mt < 2; ++mt) {
            const int tau = mt * 16 + l16;
            const f16* ap = Asrc + (size_t)(t0 + (tau >> 2)) * (B_ * H_) +
                            (size_t)(bb0 + (tau & 3)) * H_;
#pragma unroll
            for (int ki = 0; ki < 4; ++ki)
                af[mt][ki] = *(const f16x8*)(ap + ki * 32 + hi * 8);
        }
#pragma unroll
        for (int nt = 0; nt < 4; ++nt) {
            const int n = wid * 64 + nt * 16 + l16;
            f16x8 bf[4];
#pragma unroll
            for (int ki = 0; ki < 4; ++ki)
                bf[ki] = load8cvt(Wih + n * 128 + ki * 32 + hi * 8);
            f32x4 za0 = { 0.f, 0.f, 0.f, 0.f };
            f32x4 za1 = { 0.f, 0.f, 0.f, 0.f };
#pragma unroll
            for (int ki = 0; ki < 4; ++ki) {
                za0 = __builtin_amdgcn_mfma_f32_16x16x32_f16(af[0][ki], bf[ki], za0, 0, 0, 0);
                za1 = __builtin_amdgcn_mfma_f32_16x16x32_f16(af[1][ki], bf[ki], za1, 0, 0, 0);
            }
#pragma unroll
            for (int j = 0; j < 4; ++j) {
                zx_wr(ZX, hi * 4 + j, wid * 64 + nt * 16 + l16, (f16)za0[j]);
                zx_wr(ZX, 16 + hi * 4 + j, wid * 64 + nt * 16 + l16, (f16)za1[j]);
            }
            __builtin_amdgcn_sched_barrier(0);
        }
    };

    auto slots = [&](int t0, bool writeYH) {
        for (int it = 0; it < CH_; ++it) {
            const int t = t0 + it;
            f16x8 ha[4];
#pragma unroll
            for (int ki = 0; ki < 4; ++ki)
                ha[ki] = lds_rd8(HL[t & 1], l16 >> 2, ki * 64 + hi * 16);
            f32x4 acc[4];
#pragma unroll
            for (int g = 0; g < 4; ++g) {
                f32x4 bv = { biasg[g], biasg[g], biasg[g], biasg[g] };
                acc[g] = bv;
            }
#pragma unroll
            for (int ki = 0; ki < 4; ++ki)
#pragma unroll
                for (int g = 0; g < 4; ++g)
                    acc[g] = __builtin_amdgcn_mfma_f32_16x16x32_f16(ha[ki], whh[g][ki], acc[g], 0, 0, 0);
            float zi = acc[0][0] + zx_rd(ZX, it * 4 + hi, 0 + mycol);
            float zf = acc[1][0] + zx_rd(ZX, it * 4 + hi, 128 + mycol);
            float zg = acc[2][0] + zx_rd(ZX, it * 4 + hi, 256 + mycol);
            float zo = acc[3][0] + zx_rd(ZX, it * 4 + hi, 384 + mycol);
            c = sig_f(zf) * c + sig_f(zi) * tanh_f(zg);
            h = sig_f(zo) * tanh_f(c);
            lds_wr1(HL[(t + 1) & 1], hi, mycol, (f16)h);
            if (writeYH) lds_wr1(YH, it * 4 + hi, mycol, (f16)h);
            __syncthreads();
        }
    };

    if (producer) {
        for (int k = 0; k < T_ / CH_; ++k) {
            const int t0 = k * CH_;
            zgemm(xb, t0);
            __syncthreads();
            slots(t0, true);
            // flush YH -> ys (coalesced), publish chunk k
            {
                int tau = tid >> 4, cw8 = tid & 15;
                f16x8 v = lds_rd8(YH, tau, cw8 * 16);
                *(f16x8*)(ys + (size_t)(t0 + (tau >> 2)) * (B_ * H_) +
                          (size_t)(bb0 + (tau & 3)) * H_ + cw8 * 8) = v;
            }
            __threadfence();
            __syncthreads();
            if (tid == 0)
                __hip_atomic_store(&flags[p], k + 1, __ATOMIC_RELEASE,
                                   __HIP_MEMORY_SCOPE_AGENT);
        }
    } else {
        for (int k = 0; k < T_ / CH_; ++k) {
            const int t0 = k * CH_;
            if (tid == 0) {
                while (__hip_atomic_load(&flags[p], __ATOMIC_ACQUIRE,
                                         __HIP_MEMORY_SCOPE_AGENT) < k + 1)
                    __builtin_amdgcn_s_sleep(8);
            }
            __syncthreads();
            zgemm(ys, t0);
            __syncthreads();
            slots(t0, false);
        }
        hfin[(size_t)(bb0 + hi) * H_ + mycol] = h;
    }
}

// ---------------------------------------------------------------------------
// K3: head — LayerNorm + Linear(128->32) + GELU + Linear(32->8). 4 rows/block.
// ---------------------------------------------------------------------------
__global__ __launch_bounds__(256) void head_k(
    const float* __restrict__ hfin,
    const float* __restrict__ lng, const float* __restrict__ lnb,
    const float* __restrict__ hw1, const float* __restrict__ hb1,
    const float* __restrict__ hw2, const float* __restrict__ hb2,
    float* __restrict__ outp)
{
    __shared__ float HN[4][128];
    __shared__ float G[4][32];
    const int tid = threadIdx.x, lane = tid & 63, wid = tid >> 6;
    const int b = blockIdx.x * 4 + wid;
    float v0 = hfin[b * 128 + lane], v1 = hfin[b * 128 + 64 + lane];
    float s = v0 + v1;
#pragma unroll
    for (int m = 1; m < 64; m <<= 1) s += __shfl_xor(s, m);
    float mu = s * (1.f / 128.f);
    float d0 = v0 - mu, d1 = v1 - mu;
    float q = d0 * d0 + d1 * d1;
#pragma unroll
    for (int m = 1; m < 64; m <<= 1) q += __shfl_xor(q, m);
    float rs = rsqrtf(q * (1.f / 128.f) + 1e-5f);
    HN[wid][lane] = d0 * rs * lng[lane] + lnb[lane];
    HN[wid][64 + lane] = d1 * rs * lng[64 + lane] + lnb[64 + lane];
    __syncthreads();
    if (tid < 128) {
        int row = tid >> 5, o = tid & 31;
        float a = hb1[o];
#pragma unroll 4
        for (int k = 0; k < 128; ++k) a = fmaf(HN[row][k], hw1[o * 128 + k], a);
        G[row][o] = gelu_f(a);
    }
    __syncthreads();
    if (tid < 32) {
        int row = tid >> 3, oo = tid & 7;
        float a = hb2[oo];
#pragma unroll
        for (int k = 0; k < 32; ++k) a = fmaf(G[row][k], hw2[oo * 32 + k], a);
        outp[(size_t)(blockIdx.x * 4 + row) * 8 + oo] = a;
    }
}

extern "C" void kernel_launch(void* const* d_in, const int* in_sizes, int n_in,
                              void* d_out, int out_size, void* d_ws, size_t ws_size,
                              hipStream_t stream) {
    (void)in_sizes; (void)n_in; (void)out_size; (void)ws_size;
    const float* src  = (const float*)d_in[0];
    const float* w0   = (const float*)d_in[1];
    const float* b0   = (const float*)d_in[2];
    const float* w1   = (const float*)d_in[3];
    const float* b1   = (const float*)d_in[4];
    const float* w2   = (const float*)d_in[5];
    const float* b2   = (const float*)d_in[6];
    const float* w3   = (const float*)d_in[7];
    const float* b3   = (const float*)d_in[8];
    const float* pos  = (const float*)d_in[9];
    const float* Wih0 = (const float*)d_in[10];
    const float* Whh0 = (const float*)d_in[11];
    const float* bih0 = (const float*)d_in[12];
    const float* bhh0 = (const float*)d_in[13];
    const float* Wih1 = (const float*)d_in[14];
    const float* Whh1 = (const float*)d_in[15];
    const float* bih1 = (const float*)d_in[16];
    const float* bhh1 = (const float*)d_in[17];
    const float* lng  = (const float*)d_in[18];
    const float* lnb  = (const float*)d_in[19];
    const float* hw1  = (const float*)d_in[20];
    const float* hb1  = (const float*)d_in[21];
    const float* hw2  = (const float*)d_in[22];
    const float* hb2  = (const float*)d_in[23];
    float* outp = (float*)d_out;

    f16* xbuf = (f16*)d_ws;                                  // (T,B,H) f16 = 128 MB
    float* hfin = (float*)((char*)d_ws + (size_t)134217728); // 512KB
    int* flags = (int*)((char*)d_ws + (size_t)134742016);    // 1KB

    hipMemsetAsync(flags, 0, 1024, stream);
    conv_k<<<dim3(8192), dim3(512), 0, stream>>>(
        src, w0, b0, w1, b1, w2, b2, w3, b3, pos, xbuf);
    lstm_pc_k<<<dim3(512), dim3(512), 0, stream>>>(
        xbuf, Wih0, Whh0, bih0, bhh0, Wih1, Whh1, bih1, bhh1,
        xbuf /* ys in-place */, flags, hfin);
    head_k<<<dim3(256), dim3(256), 0, stream>>>(
        hfin, lng, lnb, hw1, hb1, hw2, hb2, outp);
}

// Round 15
// 2720.666 us; speedup vs baseline: 1.3267x; 1.3267x over previous
//
#include <hip/hip_runtime.h>
#include <hip/hip_bf16.h>
#include <cstdint>

#define T_ 512
#define B_ 1024
#define D_ 6
#define H_ 128
#define CH_ 8   // chunk timesteps in lstm kernel
#define CT_ 16  // timesteps per conv block

typedef _Float16 f16;
typedef _Float16 f16x8 __attribute__((ext_vector_type(8)));
typedef float f32x4 __attribute__((ext_vector_type(4)));

// branch-free erf (Abramowitz-Stegun 7.1.26, max abs err 1.5e-7)
__device__ __forceinline__ float erf_f(float x) {
    float ax = fabsf(x);
    float t = __builtin_amdgcn_rcpf(fmaf(0.3275911f, ax, 1.f));
    float p = fmaf(t, 1.061405429f, -1.453152027f);
    p = fmaf(t, p, 1.421413741f);
    p = fmaf(t, p, -0.284496736f);
    p = fmaf(t, p, 0.254829592f);
    p = p * t;
    float e = __builtin_amdgcn_exp2f(-ax * ax * 1.4426950408889634f);
    float r = 1.f - p * e;
    return copysignf(r, x);
}
__device__ __forceinline__ float gelu_f(float x) {
    return 0.5f * x * (1.f + erf_f(x * 0.7071067811865476f));
}
__device__ __forceinline__ float sig_f(float x) {
    return __builtin_amdgcn_rcpf(1.f + __builtin_amdgcn_exp2f(-1.4426950408889634f * x));
}
__device__ __forceinline__ float tanh_f(float x) {
    return 2.f * sig_f(2.f * x) - 1.f;
}
__device__ __forceinline__ f16x8 load8cvt(const float* p) {
    float4 a = ((const float4*)p)[0];
    float4 b = ((const float4*)p)[1];
    f16x8 r = { (f16)a.x, (f16)a.y, (f16)a.z, (f16)a.w,
                (f16)b.x, (f16)b.y, (f16)b.z, (f16)b.w };
    return r;
}
// LICM-defeating launder for the per-chunk-streamed Wih pointers (R8 lesson:
// unlaundered streams get hoisted on top of 128 resident frag regs -> spills).
__device__ __forceinline__ const float* launder(const float* p) {
    asm volatile("" : "+s"(p));
    return p;
}
// LDS tiles: row-major [rows][128] f16, 256B row stride, 16B-chunk XOR swizzle
__device__ __forceinline__ f16x8 lds_rd8(const f16* base, int row, int cb) {
    const char* p = (const char*)base + row * 256 + (cb ^ ((row & 7) << 4));
    return *(const f16x8*)p;
}
__device__ __forceinline__ void lds_wr1(f16* base, int row, int col, f16 v) {
    char* p = (char*)base + row * 256 + ((col * 2) ^ ((row & 7) << 4));
    *(f16*)p = v;
}
// ZX tile: [32 rows][512 cols] f16, 1024B row stride, same XOR swizzle
__device__ __forceinline__ void zx_wr(f16* base, int row, int col, f16 v) {
    char* p = (char*)base + row * 1024 + ((col * 2) ^ ((row & 7) << 4));
    *(f16*)p = v;
}
__device__ __forceinline__ float zx_rd(const f16* base, int row, int col) {
    const char* p = (const char*)base + row * 1024 + ((col * 2) ^ ((row & 7) << 4));
    return (float)*(const f16*)p;
}

// ---------------------------------------------------------------------------
// K1: conv stack STANDALONE (R13-proven, ~144us). 8192 blocks x 512 thr.
// ---------------------------------------------------------------------------
__global__ __launch_bounds__(512) void conv_k(
    const float* __restrict__ src,
    const float* __restrict__ w0p, const float* __restrict__ b0p,
    const float* __restrict__ w1p, const float* __restrict__ b1p,
    const float* __restrict__ w2p, const float* __restrict__ b2p,
    const float* __restrict__ w3p, const float* __restrict__ b3p,
    const float* __restrict__ posp, f16* __restrict__ xout)
{
    __shared__ f16 XA0[64 * 128];   // 16KB
    __shared__ f16 XA1[64 * 128];   // 16KB
    const int tid = threadIdx.x;
    const int lane = tid & 63, wid = tid >> 6;
    const int l16 = lane & 15, hi = lane >> 4;
    const int t0 = (blockIdx.x & 31) * CT_;
    const int bb0 = (blockIdx.x >> 5) * 4;
    const int mycol = wid * 16 + l16;

    f16x8 cw[3][4];
    {
        const float* wp[3] = { w1p, w2p, w3p };
#pragma unroll
        for (int L = 0; L < 3; ++L)
#pragma unroll
            for (int ki = 0; ki < 4; ++ki)
                cw[L][ki] = load8cvt(wp[L] + mycol * 128 + ki * 32 + hi * 8);
    }
    const int col0 = tid & 127;
    const int r0 = tid >> 7;
    float w0c[6], b0c;
#pragma unroll
    for (int k = 0; k < 6; ++k) w0c[k] = w0p[col0 * 6 + k];
    b0c = b0p[col0];
    const float b1c = b1p[mycol], b2c = b2p[mycol], b3c = b3p[mycol];

    {
        const float2* sp0 = (const float2*)src + ((size_t)(bb0 + r0) * T_ + t0) * 3;
#pragma unroll
        for (int it = 0; it < CT_; ++it) {
            float2 a = sp0[it * 3 + 0], b = sp0[it * 3 + 1], c2 = sp0[it * 3 + 2];
            float acc = b0c;
            acc = fmaf(a.x, w0c[0], acc);
            acc = fmaf(a.y, w0c[1], acc);
            acc = fmaf(b.x, w0c[2], acc);
            acc = fmaf(b.y, w0c[3], acc);
            acc = fmaf(c2.x, w0c[4], acc);
            acc = fmaf(c2.y, w0c[5], acc);
            lds_wr1(XA0, it * 4 + r0, col0, (f16)gelu_f(acc));
        }
    }
    __syncthreads();

    auto conv_mfma = [&](const f16* Xin, f16* Xout, int L, float bc, bool addpos) {
#pragma unroll
        for (int mt = 0; mt < 4; ++mt) {
            f16x8 af[4];
#pragma unroll
            for (int ki = 0; ki < 4; ++ki)
                af[ki] = lds_rd8(Xin, mt * 16 + l16, ki * 64 + hi * 16);
            f32x4 acc = { bc, bc, bc, bc };
#pragma unroll
            for (int ki = 0; ki < 4; ++ki)
                acc = __builtin_amdgcn_mfma_f32_16x16x32_f16(af[ki], cw[L][ki], acc, 0, 0, 0);
            float pv = 0.f;
            if (addpos) pv = posp[(t0 + mt * 4 + hi) * 128 + mycol];
#pragma unroll
            for (int j = 0; j < 4; ++j)
                lds_wr1(Xout, mt * 16 + hi * 4 + j, mycol, (f16)(gelu_f(acc[j]) + pv));
        }
    };
    conv_mfma(XA0, XA1, 0, b1c, false);
    __syncthreads();
    conv_mfma(XA1, XA0, 1, b2c, false);
    __syncthreads();
    conv_mfma(XA0, XA1, 2, b3c, true);   // + pos_embed
    __syncthreads();

#pragma unroll
    for (int pass = 0; pass < 2; ++pass) {
        int u = pass * 512 + tid;
        int tau = u >> 4, cw8 = u & 15;
        f16x8 v = lds_rd8(XA1, tau, cw8 * 16);
        *(f16x8*)(xout + (size_t)(t0 + (tau >> 2)) * (B_ * H_) +
                  (size_t)(bb0 + (tau & 3)) * H_ + cw8 * 8) = v;
    }
}

// ---------------------------------------------------------------------------
// K2: DUAL-LAYER LSTM, in-block overlap (R10 structure minus conv/cw — the
// pieces that blew its register budget). 256 blocks x 512 thr, 4 rows/block.
// Resident frags: whh0+whh1 = 128 regs exactly (+~110 arch transients < 256
// unified budget; R10 failed at ~304). Per chunk k:
//   PZ: zgemm0 (x chunk k from global @ Wih0^T -> ZX0, Wih0 laundered-
//       streamed) ; k>0: zgemm1 (YH[(k-1)&1] LDS @ Wih1^T -> ZX1).
//   8 dual slots: lstm0 step t -> HL0,YH[k&1]; k>0: lstm1 step t-8 -> HL1.
//       Two independent 4-deep MFMA chains interleave (ILP).
// Tail: zgemm1 + 8 lstm1 slots; hfin = h1. ys NEVER touches global: phases
// 1152 -> ~640 AND the 134MB ys round-trip is gone. Legit global writes =
// hfin 512KB only -> WRITE_SIZE is an unambiguous spill tripwire.
// ---------------------------------------------------------------------------
__global__ __launch_bounds__(512) void lstm_dual_k(
    const f16* __restrict__ xb,
    const float* __restrict__ Wih0, const float* __restrict__ Whh0,
    const float* __restrict__ bih0, const float* __restrict__ bhh0,
    const float* __restrict__ Wih1, const float* __restrict__ Whh1,
    const float* __restrict__ bih1, const float* __restrict__ bhh1,
    float* __restrict__ hfin)
{
    __shared__ f16 ZX0[32 * 512];         // 32KB
    __shared__ f16 ZX1[32 * 512];         // 32KB
    __shared__ f16 YH[2][32 * 128];       // 16KB h0 history ping-pong
    __shared__ f16 HL0[2][4 * 128];       // 2KB
    __shared__ f16 HL1[2][4 * 128];       // 2KB   => 84KB

    const int tid = threadIdx.x;
    const int lane = tid & 63, wid = tid >> 6;
    const int l16 = lane & 15, hi = lane >> 4;
    const int bb0 = blockIdx.x * 4;
    const int mycol = wid * 16 + l16;

    f16x8 whh0[4][4], whh1[4][4];
    float bg0[4], bg1[4];
#pragma unroll
    for (int g = 0; g < 4; ++g) {
        int n = g * 128 + mycol;
        bg0[g] = bih0[n] + bhh0[n];
        bg1[g] = bih1[n] + bhh1[n];
#pragma unroll
        for (int ki = 0; ki < 4; ++ki) {
            whh0[g][ki] = load8cvt(Whh0 + n * 128 + ki * 32 + hi * 8);
            whh1[g][ki] = load8cvt(Whh1 + n * 128 + ki * 32 + hi * 8);
        }
    }
    for (int i = tid; i < 2 * 4 * 128; i += 512) {
        ((f16*)HL0)[i] = (f16)0.f;
        ((f16*)HL1)[i] = (f16)0.f;
    }
    float c0 = 0.f, h0 = 0.f, c1 = 0.f, h1 = 0.f;
    __syncthreads();

    // zgemm: A-frags provided by caller, B streamed from laundered Wg -> ZXout
    auto zgemm_core = [&](const f16x8 (&af)[2][4], const float* Wg0, f16* ZXout) {
        const float* Wg = launder(Wg0);
#pragma unroll
        for (int nt = 0; nt < 4; ++nt) {
            const int n = wid * 64 + nt * 16 + l16;
            f16x8 bf[4];
#pragma unroll
            for (int ki = 0; ki < 4; ++ki)
                bf[ki] = load8cvt(Wg + n * 128 + ki * 32 + hi * 8);
            f32x4 za0 = { 0.f, 0.f, 0.f, 0.f };
            f32x4 za1 = { 0.f, 0.f, 0.f, 0.f };
#pragma unroll
            for (int ki = 0; ki < 4; ++ki) {
                za0 = __builtin_amdgcn_mfma_f32_16x16x32_f16(af[0][ki], bf[ki], za0, 0, 0, 0);
                za1 = __builtin_amdgcn_mfma_f32_16x16x32_f16(af[1][ki], bf[ki], za1, 0, 0, 0);
            }
#pragma unroll
            for (int j = 0; j < 4; ++j) {
                zx_wr(ZXout, hi * 4 + j, wid * 64 + nt * 16 + l16, (f16)za0[j]);
                zx_wr(ZXout, 16 + hi * 4 + j, wid * 64 + nt * 16 + l16, (f16)za1[j]);
            }
            __builtin_amdgcn_sched_barrier(0);
        }
    };

    // one LSTM step for one layer (16 MFMA h-side + in-register pointwise)
    auto lstep = [&](const f16* HLin, f16* HLout, const f16x8 (&whf)[4][4],
                     const float (&bg)[4], const f16* ZXp, int it,
                     float& cc, float& hh) {
        f16x8 ha[4];
#pragma unroll
        for (int ki = 0; ki < 4; ++ki)
            ha[ki] = lds_rd8(HLin, l16 >> 2, ki * 64 + hi * 16);
        f32x4 acc[4];
#pragma unroll
        for (int g = 0; g < 4; ++g) {
            f32x4 bv = { bg[g], bg[g], bg[g], bg[g] };
            acc[g] = bv;
        }
#pragma unroll
        for (int ki = 0; ki < 4; ++ki)
#pragma unroll
            for (int g = 0; g < 4; ++g)
                acc[g] = __builtin_amdgcn_mfma_f32_16x16x32_f16(ha[ki], whf[g][ki], acc[g], 0, 0, 0);
        float zi = acc[0][0] + zx_rd(ZXp, it * 4 + hi, 0 + mycol);
        float zf = acc[1][0] + zx_rd(ZXp, it * 4 + hi, 128 + mycol);
        float zg = acc[2][0] + zx_rd(ZXp, it * 4 + hi, 256 + mycol);
        float zo = acc[3][0] + zx_rd(ZXp, it * 4 + hi, 384 + mycol);
        cc = sig_f(zf) * cc + sig_f(zi) * tanh_f(zg);
        hh = sig_f(zo) * tanh_f(cc);
        lds_wr1(HLout, hi, mycol, (f16)hh);
    };

    for (int k = 0; k < T_ / CH_; ++k) {
        const int t0 = k * CH_;
        // --- PZ: zgemm0 (A from global x) and, k>0, zgemm1 (A from YH prev) ---
        {
            f16x8 af[2][4];
#pragma unroll
            for (int mt = 0; mt < 2; ++mt) {
                const int tau = mt * 16 + l16;
                const f16* ap = xb + (size_t)(t0 + (tau >> 2)) * (B_ * H_) +
                                (size_t)(bb0 + (tau & 3)) * H_;
#pragma unroll
                for (int ki = 0; ki < 4; ++ki)
                    af[mt][ki] = *(const f16x8*)(ap + ki * 32 + hi * 8);
            }
            zgemm_core(af, Wih0, ZX0);
        }
        if (k > 0) {
            f16x8 af[2][4];
#pragma unroll
            for (int mt = 0; mt < 2; ++mt)
#pragma unroll
                for (int ki = 0; ki < 4; ++ki)
                    af[mt][ki] = lds_rd8(YH[(k ^ 1) & 1], mt * 16 + l16, ki * 64 + hi * 16);
            zgemm_core(af, Wih1, ZX1);
        }
        __syncthreads();
        // --- 8 dual slots ---
        for (int it = 0; it < CH_; ++it) {
            const int t = t0 + it;
            lstep(HL0[t & 1], HL0[(t + 1) & 1], whh0, bg0, ZX0, it, c0, h0);
            lds_wr1(YH[k & 1], it * 4 + hi, mycol, (f16)h0);
            if (k > 0)
                lstep(HL1[t & 1], HL1[(t + 1) & 1], whh1, bg1, ZX1, it, c1, h1);
            __syncthreads();
        }
    }
    // --- tail: lstm1 on the last chunk's YH (steps 504..511) ---
    {
        f16x8 af[2][4];
#pragma unroll
        for (int mt = 0; mt < 2; ++mt)
#pragma unroll
            for (int ki = 0; ki < 4; ++ki)
                af[mt][ki] = lds_rd8(YH[(T_ / CH_ - 1) & 1], mt * 16 + l16, ki * 64 + hi * 16);
        zgemm_core(af, Wih1, ZX1);
    }
    __syncthreads();
    for (int it = 0; it < CH_; ++it) {
        const int t = (T_ - CH_) + it;
        lstep(HL1[t & 1], HL1[(t + 1) & 1], whh1, bg1, ZX1, it, c1, h1);
        __syncthreads();
    }
    hfin[(size_t)(bb0 + hi) * H_ + mycol] = h1;
}

// ---------------------------------------------------------------------------
// K3: head — LayerNorm + Linear(128->32) + GELU + Linear(32->8). 4 rows/block.
// ---------------------------------------------------------------------------
__global__ __launch_bounds__(256) void head_k(
    const float* __restrict__ hfin,
    const float* __restrict__ lng, const float* __restrict__ lnb,
    const float* __restrict__ hw1, const float* __restrict__ hb1,
    const float* __restrict__ hw2, const float* __restrict__ hb2,
    float* __restrict__ outp)
{
    __shared__ float HN[4][128];
    __shared__ float G[4][32];
    const int tid = threadIdx.x, lane = tid & 63, wid = tid >> 6;
    const int b = blockIdx.x * 4 + wid;
    float v0 = hfin[b * 128 + lane], v1 = hfin[b * 128 + 64 + lane];
    float s = v0 + v1;
#pragma unroll
    for (int m = 1; m < 64; m <<= 1) s += __shfl_xor(s, m);
    float mu = s * (1.f / 128.f);
    float d0 = v0 - mu, d1 = v1 - mu;
    float q = d0 * d0 + d1 * d1;
#pragma unroll
    for (int m = 1; m < 64; m <<= 1) q += __shfl_xor(q, m);
    float rs = rsqrtf(q * (1.f / 128.f) + 1e-5f);
    HN[wid][lane] = d0 * rs * lng[lane] + lnb[lane];
    HN[wid][64 + lane] = d1 * rs * lng[64 + lane] + lnb[64 + lane];
    __syncthreads();
    if (tid < 128) {
        int row = tid >> 5, o = tid & 31;
        float a = hb1[o];
#pragma unroll 4
        for (int k = 0; k < 128; ++k) a = fmaf(HN[row][k], hw1[o * 128 + k], a);
        G[row][o] = gelu_f(a);
    }
    __syncthreads();
    if (tid < 32) {
        int row = tid >> 3, oo = tid & 7;
        float a = hb2[oo];
#pragma unroll
        for (int k = 0; k < 32; ++k) a = fmaf(G[row][k], hw2[oo * 32 + k], a);
        outp[(size_t)(blockIdx.x * 4 + row) * 8 + oo] = a;
    }
}

extern "C" void kernel_launch(void* const* d_in, const int* in_sizes, int n_in,
                              void* d_out, int out_size, void* d_ws, size_t ws_size,
                              hipStream_t stream) {
    (void)in_sizes; (void)n_in; (void)out_size; (void)ws_size;
    const float* src  = (const float*)d_in[0];
    const float* w0   = (const float*)d_in[1];
    const float* b0   = (const float*)d_in[2];
    const float* w1   = (const float*)d_in[3];
    const float* b1   = (const float*)d_in[4];
    const float* w2   = (const float*)d_in[5];
    const float* b2   = (const float*)d_in[6];
    const float* w3   = (const float*)d_in[7];
    const float* b3   = (const float*)d_in[8];
    const float* pos  = (const float*)d_in[9];
    const float* Wih0 = (const float*)d_in[10];
    const float* Whh0 = (const float*)d_in[11];
    const float* bih0 = (const float*)d_in[12];
    const float* bhh0 = (const float*)d_in[13];
    const float* Wih1 = (const float*)d_in[14];
    const float* Whh1 = (const float*)d_in[15];
    const float* bih1 = (const float*)d_in[16];
    const float* bhh1 = (const float*)d_in[17];
    const float* lng  = (const float*)d_in[18];
    const float* lnb  = (const float*)d_in[19];
    const float* hw1  = (const float*)d_in[20];
    const float* hb1  = (const float*)d_in[21];
    const float* hw2  = (const float*)d_in[22];
    const float* hb2  = (const float*)d_in[23];
    float* outp = (float*)d_out;

    f16* xbuf = (f16*)d_ws;                                  // (T,B,H) f16 = 128 MB
    float* hfin = (float*)((char*)d_ws + (size_t)134217728); // 512KB

    conv_k<<<dim3(8192), dim3(512), 0, stream>>>(
        src, w0, b0, w1, b1, w2, b2, w3, b3, pos, xbuf);
    lstm_dual_k<<<dim3(256), dim3(512), 0, stream>>>(
        xbuf, Wih0, Whh0, bih0, bhh0, Wih1, Whh1, bih1, bhh1, hfin);
    head_k<<<dim3(256), dim3(256), 0, stream>>>(
        hfin, lng, lnb, hw1, hb1, hw2, hb2, outp);
}

// Round 16
// 2634.650 us; speedup vs baseline: 1.3700x; 1.0326x over previous
//
#include <hip/hip_runtime.h>
#include <hip/hip_bf16.h>
#include <cstdint>

#define T_ 512
#define B_ 1024
#define D_ 6
#define H_ 128
#define CH_ 8   // chunk timesteps in lstm kernel
#define CT_ 16  // timesteps per conv block

typedef _Float16 f16;
typedef _Float16 f16x8 __attribute__((ext_vector_type(8)));
typedef float f32x4 __attribute__((ext_vector_type(4)));

// branch-free erf (Abramowitz-Stegun 7.1.26, max abs err 1.5e-7)
__device__ __forceinline__ float erf_f(float x) {
    float ax = fabsf(x);
    float t = __builtin_amdgcn_rcpf(fmaf(0.3275911f, ax, 1.f));
    float p = fmaf(t, 1.061405429f, -1.453152027f);
    p = fmaf(t, p, 1.421413741f);
    p = fmaf(t, p, -0.284496736f);
    p = fmaf(t, p, 0.254829592f);
    p = p * t;
    float e = __builtin_amdgcn_exp2f(-ax * ax * 1.4426950408889634f);
    float r = 1.f - p * e;
    return copysignf(r, x);
}
__device__ __forceinline__ float gelu_f(float x) {
    return 0.5f * x * (1.f + erf_f(x * 0.7071067811865476f));
}
__device__ __forceinline__ float sig_f(float x) {
    return __builtin_amdgcn_rcpf(1.f + __builtin_amdgcn_exp2f(-1.4426950408889634f * x));
}
__device__ __forceinline__ float tanh_f(float x) {
    return 2.f * sig_f(2.f * x) - 1.f;
}
__device__ __forceinline__ f16x8 load8cvt(const float* p) {
    float4 a = ((const float4*)p)[0];
    float4 b = ((const float4*)p)[1];
    f16x8 r = { (f16)a.x, (f16)a.y, (f16)a.z, (f16)a.w,
                (f16)b.x, (f16)b.y, (f16)b.z, (f16)b.w };
    return r;
}
// LICM-defeating launder for the per-chunk-streamed Wih pointers
__device__ __forceinline__ const float* launder(const float* p) {
    asm volatile("" : "+s"(p));
    return p;
}
// LDS tiles: row-major [rows][128] f16, 256B row stride, 16B-chunk XOR swizzle
__device__ __forceinline__ f16x8 lds_rd8(const f16* base, int row, int cb) {
    const char* p = (const char*)base + row * 256 + (cb ^ ((row & 7) << 4));
    return *(const f16x8*)p;
}
__device__ __forceinline__ void lds_wr1(f16* base, int row, int col, f16 v) {
    char* p = (char*)base + row * 256 + ((col * 2) ^ ((row & 7) << 4));
    *(f16*)p = v;
}
// ZX tile: [32 rows][512 cols] f16, 1024B row stride, same XOR swizzle
__device__ __forceinline__ void zx_wr(f16* base, int row, int col, f16 v) {
    char* p = (char*)base + row * 1024 + ((col * 2) ^ ((row & 7) << 4));
    *(f16*)p = v;
}
__device__ __forceinline__ float zx_rd(const f16* base, int row, int col) {
    const char* p = (const char*)base + row * 1024 + ((col * 2) ^ ((row & 7) << 4));
    return (float)*(const f16*)p;
}

// ---------------------------------------------------------------------------
// K1: conv stack STANDALONE (R13-proven, ~144us). 8192 blocks x 512 thr.
// ---------------------------------------------------------------------------
__global__ __launch_bounds__(512) void conv_k(
    const float* __restrict__ src,
    const float* __restrict__ w0p, const float* __restrict__ b0p,
    const float* __restrict__ w1p, const float* __restrict__ b1p,
    const float* __restrict__ w2p, const float* __restrict__ b2p,
    const float* __restrict__ w3p, const float* __restrict__ b3p,
    const float* __restrict__ posp, f16* __restrict__ xout)
{
    __shared__ f16 XA0[64 * 128];   // 16KB
    __shared__ f16 XA1[64 * 128];   // 16KB
    const int tid = threadIdx.x;
    const int lane = tid & 63, wid = tid >> 6;
    const int l16 = lane & 15, hi = lane >> 4;
    const int t0 = (blockIdx.x & 31) * CT_;
    const int bb0 = (blockIdx.x >> 5) * 4;
    const int mycol = wid * 16 + l16;

    f16x8 cw[3][4];
    {
        const float* wp[3] = { w1p, w2p, w3p };
#pragma unroll
        for (int L = 0; L < 3; ++L)
#pragma unroll
            for (int ki = 0; ki < 4; ++ki)
                cw[L][ki] = load8cvt(wp[L] + mycol * 128 + ki * 32 + hi * 8);
    }
    const int col0 = tid & 127;
    const int r0 = tid >> 7;
    float w0c[6], b0c;
#pragma unroll
    for (int k = 0; k < 6; ++k) w0c[k] = w0p[col0 * 6 + k];
    b0c = b0p[col0];
    const float b1c = b1p[mycol], b2c = b2p[mycol], b3c = b3p[mycol];

    {
        const float2* sp0 = (const float2*)src + ((size_t)(bb0 + r0) * T_ + t0) * 3;
#pragma unroll
        for (int it = 0; it < CT_; ++it) {
            float2 a = sp0[it * 3 + 0], b = sp0[it * 3 + 1], c2 = sp0[it * 3 + 2];
            float acc = b0c;
            acc = fmaf(a.x, w0c[0], acc);
            acc = fmaf(a.y, w0c[1], acc);
            acc = fmaf(b.x, w0c[2], acc);
            acc = fmaf(b.y, w0c[3], acc);
            acc = fmaf(c2.x, w0c[4], acc);
            acc = fmaf(c2.y, w0c[5], acc);
            lds_wr1(XA0, it * 4 + r0, col0, (f16)gelu_f(acc));
        }
    }
    __syncthreads();

    auto conv_mfma = [&](const f16* Xin, f16* Xout, int L, float bc, bool addpos) {
#pragma unroll
        for (int mt = 0; mt < 4; ++mt) {
            f16x8 af[4];
#pragma unroll
            for (int ki = 0; ki < 4; ++ki)
                af[ki] = lds_rd8(Xin, mt * 16 + l16, ki * 64 + hi * 16);
            f32x4 acc = { bc, bc, bc, bc };
#pragma unroll
            for (int ki = 0; ki < 4; ++ki)
                acc = __builtin_amdgcn_mfma_f32_16x16x32_f16(af[ki], cw[L][ki], acc, 0, 0, 0);
            float pv = 0.f;
            if (addpos) pv = posp[(t0 + mt * 4 + hi) * 128 + mycol];
#pragma unroll
            for (int j = 0; j < 4; ++j)
                lds_wr1(Xout, mt * 16 + hi * 4 + j, mycol, (f16)(gelu_f(acc[j]) + pv));
        }
    };
    conv_mfma(XA0, XA1, 0, b1c, false);
    __syncthreads();
    conv_mfma(XA1, XA0, 1, b2c, false);
    __syncthreads();
    conv_mfma(XA0, XA1, 2, b3c, true);   // + pos_embed
    __syncthreads();

#pragma unroll
    for (int pass = 0; pass < 2; ++pass) {
        int u = pass * 512 + tid;
        int tau = u >> 4, cw8 = u & 15;
        f16x8 v = lds_rd8(XA1, tau, cw8 * 16);
        *(f16x8*)(xout + (size_t)(t0 + (tau >> 2)) * (B_ * H_) +
                  (size_t)(bb0 + (tau & 3)) * H_ + cw8 * 8) = v;
    }
}

// ---------------------------------------------------------------------------
// K2: DUAL-LAYER LSTM, 256-THREAD blocks (4 waves = 1 wave/SIMD = 1 block/CU
// -> 512 regs/lane budget; m08: no spill through ~450). whh0+whh1 = 64 f16x8
// = 256 VGPRs resident LEGALLY (512-thr blocks cap at 256 total incl. AGPR —
// the root cause of R8/R10/R15 spills). Each wave covers 2 n-tiles per gate
// (col = n2*64 + wid*16 + l16); each lane owns 2 (c,h) pairs per layer.
// Per chunk k: PZ zgemm0 (x->ZX0) + k>0 zgemm1 (YH prev ->ZX1); 8 dual slots
// (lstm0 t, lstm1 t-8). Tail: zgemm1 + 8 lstm1 slots. ys never in global.
// Legit global writes = hfin 512KB -> WRITE_SIZE is the spill tripwire.
// ---------------------------------------------------------------------------
__global__ __launch_bounds__(256, 1) void lstm_dual_k(
    const f16* __restrict__ xb,
    const float* __restrict__ Wih0, const float* __restrict__ Whh0,
    const float* __restrict__ bih0, const float* __restrict__ bhh0,
    const float* __restrict__ Wih1, const float* __restrict__ Whh1,
    const float* __restrict__ bih1, const float* __restrict__ bhh1,
    float* __restrict__ hfin)
{
    __shared__ f16 ZX0[32 * 512];         // 32KB
    __shared__ f16 ZX1[32 * 512];         // 32KB
    __shared__ f16 YH[2][32 * 128];       // 16KB h0 history ping-pong
    __shared__ f16 HL0[2][4 * 128];       // 2KB
    __shared__ f16 HL1[2][4 * 128];       // 2KB   => 84KB

    const int tid = threadIdx.x;
    const int lane = tid & 63, wid = tid >> 6;   // wid 0..3
    const int l16 = lane & 15, hi = lane >> 4;
    const int bb0 = blockIdx.x * 4;

    // resident h-side frags for BOTH layers: [2][4][2][4] f16x8 = 256 VGPR
    f16x8 whh[2][4][2][4];
    float bg[2][4][2];
    {
        const float* WhhA[2] = { Whh0, Whh1 };
        const float* bihA[2] = { bih0, bih1 };
        const float* bhhA[2] = { bhh0, bhh1 };
#pragma unroll
        for (int l = 0; l < 2; ++l)
#pragma unroll
            for (int g = 0; g < 4; ++g)
#pragma unroll
                for (int n2 = 0; n2 < 2; ++n2) {
                    int n = g * 128 + n2 * 64 + wid * 16 + l16;
                    bg[l][g][n2] = bihA[l][n] + bhhA[l][n];
#pragma unroll
                    for (int ki = 0; ki < 4; ++ki)
                        whh[l][g][n2][ki] = load8cvt(WhhA[l] + n * 128 + ki * 32 + hi * 8);
                }
    }
    for (int i = tid; i < 2 * 4 * 128; i += 256) {
        ((f16*)HL0)[i] = (f16)0.f;
        ((f16*)HL1)[i] = (f16)0.f;
    }
    float c0[2] = { 0.f, 0.f }, h0[2] = { 0.f, 0.f };
    float c1[2] = { 0.f, 0.f }, h1[2] = { 0.f, 0.f };
    __syncthreads();

    // zgemm: A-frags given, B streamed from laundered Wg; 4 waves x 8 n-tiles
    auto zgemm_core = [&](const f16x8 (&af)[2][4], const float* Wg0, f16* ZXout) {
        const float* Wg = launder(Wg0);
#pragma unroll
        for (int nt = 0; nt < 8; ++nt) {
            const int n = nt * 64 + wid * 16 + l16;
            f16x8 bf[4];
#pragma unroll
            for (int ki = 0; ki < 4; ++ki)
                bf[ki] = load8cvt(Wg + n * 128 + ki * 32 + hi * 8);
            f32x4 za0 = { 0.f, 0.f, 0.f, 0.f };
            f32x4 za1 = { 0.f, 0.f, 0.f, 0.f };
#pragma unroll
            for (int ki = 0; ki < 4; ++ki) {
                za0 = __builtin_amdgcn_mfma_f32_16x16x32_f16(af[0][ki], bf[ki], za0, 0, 0, 0);
                za1 = __builtin_amdgcn_mfma_f32_16x16x32_f16(af[1][ki], bf[ki], za1, 0, 0, 0);
            }
#pragma unroll
            for (int j = 0; j < 4; ++j) {
                zx_wr(ZXout, hi * 4 + j, n, (f16)za0[j]);
                zx_wr(ZXout, 16 + hi * 4 + j, n, (f16)za1[j]);
            }
            __builtin_amdgcn_sched_barrier(0);
        }
    };

    // one LSTM step for one layer: 32 h-side MFMA + 2 (c,h) pairs per lane
    auto lstep = [&](const f16* HLin, f16* HLout,
                     const f16x8 (&whf)[4][2][4], const float (&bgl)[4][2],
                     const f16* ZXp, int it,
                     float (&cc)[2], float (&hh)[2], f16* yout) {
        f16x8 ha[4];
#pragma unroll
        for (int ki = 0; ki < 4; ++ki)
            ha[ki] = lds_rd8(HLin, l16 >> 2, ki * 64 + hi * 16);
        f32x4 acc[4][2];
#pragma unroll
        for (int g = 0; g < 4; ++g)
#pragma unroll
            for (int n2 = 0; n2 < 2; ++n2) {
                f32x4 bv = { bgl[g][n2], bgl[g][n2], bgl[g][n2], bgl[g][n2] };
                acc[g][n2] = bv;
            }
#pragma unroll
        for (int ki = 0; ki < 4; ++ki)
#pragma unroll
            for (int g = 0; g < 4; ++g)
#pragma unroll
                for (int n2 = 0; n2 < 2; ++n2)
                    acc[g][n2] = __builtin_amdgcn_mfma_f32_16x16x32_f16(
                        ha[ki], whf[g][n2][ki], acc[g][n2], 0, 0, 0);
#pragma unroll
        for (int n2 = 0; n2 < 2; ++n2) {
            const int col = n2 * 64 + wid * 16 + l16;
            float zi = acc[0][n2][0] + zx_rd(ZXp, it * 4 + hi, 0 + col);
            float zf = acc[1][n2][0] + zx_rd(ZXp, it * 4 + hi, 128 + col);
            float zg = acc[2][n2][0] + zx_rd(ZXp, it * 4 + hi, 256 + col);
            float zo = acc[3][n2][0] + zx_rd(ZXp, it * 4 + hi, 384 + col);
            cc[n2] = sig_f(zf) * cc[n2] + sig_f(zi) * tanh_f(zg);
            hh[n2] = sig_f(zo) * tanh_f(cc[n2]);
            lds_wr1(HLout, hi, col, (f16)hh[n2]);
            if (yout) lds_wr1(yout, it * 4 + hi, col, (f16)hh[n2]);
        }
    };

    for (int k = 0; k < T_ / CH_; ++k) {
        const int t0 = k * CH_;
        // --- PZ: zgemm0 (A from global x); k>0: zgemm1 (A from YH prev) ---
        {
            f16x8 af[2][4];
#pragma unroll
            for (int mt = 0; mt < 2; ++mt) {
                const int tau = mt * 16 + l16;
                const f16* ap = xb + (size_t)(t0 + (tau >> 2)) * (B_ * H_) +
                                (size_t)(bb0 + (tau & 3)) * H_;
#pragma unroll
                for (int ki = 0; ki < 4; ++ki)
                    af[mt][ki] = *(const f16x8*)(ap + ki * 32 + hi * 8);
            }
            zgemm_core(af, Wih0, ZX0);
        }
        if (k > 0) {
            f16x8 af[2][4];
#pragma unroll
            for (int mt = 0; mt < 2; ++mt)
#pragma unroll
                for (int ki = 0; ki < 4; ++ki)
                    af[mt][ki] = lds_rd8(YH[(k ^ 1) & 1], mt * 16 + l16, ki * 64 + hi * 16);
            zgemm_core(af, Wih1, ZX1);
        }
        __syncthreads();
        // --- 8 dual slots ---
        for (int it = 0; it < CH_; ++it) {
            const int t = t0 + it;
            lstep(HL0[t & 1], HL0[(t + 1) & 1], whh[0], bg[0], ZX0, it, c0, h0, YH[k & 1]);
            if (k > 0)
                lstep(HL1[t & 1], HL1[(t + 1) & 1], whh[1], bg[1], ZX1, it, c1, h1, nullptr);
            __syncthreads();
        }
    }
    // --- tail: lstm1 on the last chunk's YH (steps 504..511) ---
    {
        f16x8 af[2][4];
#pragma unroll
        for (int mt = 0; mt < 2; ++mt)
#pragma unroll
            for (int ki = 0; ki < 4; ++ki)
                af[mt][ki] = lds_rd8(YH[(T_ / CH_ - 1) & 1], mt * 16 + l16, ki * 64 + hi * 16);
        zgemm_core(af, Wih1, ZX1);
    }
    __syncthreads();
    for (int it = 0; it < CH_; ++it) {
        const int t = (T_ - CH_) + it;
        lstep(HL1[t & 1], HL1[(t + 1) & 1], whh[1], bg[1], ZX1, it, c1, h1, nullptr);
        __syncthreads();
    }
#pragma unroll
    for (int n2 = 0; n2 < 2; ++n2)
        hfin[(size_t)(bb0 + hi) * H_ + n2 * 64 + wid * 16 + l16] = h1[n2];
}

// ---------------------------------------------------------------------------
// K3: head — LayerNorm + Linear(128->32) + GELU + Linear(32->8). 4 rows/block.
// ---------------------------------------------------------------------------
__global__ __launch_bounds__(256) void head_k(
    const float* __restrict__ hfin,
    const float* __restrict__ lng, const float* __restrict__ lnb,
    const float* __restrict__ hw1, const float* __restrict__ hb1,
    const float* __restrict__ hw2, const float* __restrict__ hb2,
    float* __restrict__ outp)
{
    __shared__ float HN[4][128];
    __shared__ float G[4][32];
    const int tid = threadIdx.x, lane = tid & 63, wid = tid >> 6;
    const int b = blockIdx.x * 4 + wid;
    float v0 = hfin[b * 128 + lane], v1 = hfin[b * 128 + 64 + lane];
    float s = v0 + v1;
#pragma unroll
    for (int m = 1; m < 64; m <<= 1) s += __shfl_xor(s, m);
    float mu = s * (1.f / 128.f);
    float d0 = v0 - mu, d1 = v1 - mu;
    float q = d0 * d0 + d1 * d1;
#pragma unroll
    for (int m = 1; m < 64; m <<= 1) q += __shfl_xor(q, m);
    float rs = rsqrtf(q * (1.f / 128.f) + 1e-5f);
    HN[wid][lane] = d0 * rs * lng[lane] + lnb[lane];
    HN[wid][64 + lane] = d1 * rs * lng[64 + lane] + lnb[64 + lane];
    __syncthreads();
    if (tid < 128) {
        int row = tid >> 5, o = tid & 31;
        float a = hb1[o];
#pragma unroll 4
        for (int k = 0; k < 128; ++k) a = fmaf(HN[row][k], hw1[o * 128 + k], a);
        G[row][o] = gelu_f(a);
    }
    __syncthreads();
    if (tid < 32) {
        int row = tid >> 3, oo = tid & 7;
        float a = hb2[oo];
#pragma unroll
        for (int k = 0; k < 32; ++k) a = fmaf(G[row][k], hw2[oo * 32 + k], a);
        outp[(size_t)(blockIdx.x * 4 + row) * 8 + oo] = a;
    }
}

extern "C" void kernel_launch(void* const* d_in, const int* in_sizes, int n_in,
                              void* d_out, int out_size, void* d_ws, size_t ws_size,
                              hipStream_t stream) {
    (void)in_sizes; (void)n_in; (void)out_size; (void)ws_size;
    const float* src  = (const float*)d_in[0];
    const float* w0   = (const float*)d_in[1];
    const float* b0   = (const float*)d_in[2];
    const float* w1   = (const float*)d_in[3];
    const float* b1   = (const float*)d_in[4];
    const float* w2   = (const float*)d_in[5];
    const float* b2   = (const float*)d_in[6];
    const float* w3   = (const float*)d_in[7];
    const float* b3   = (const float*)d_in[8];
    const float* pos  = (const float*)d_in[9];
    const float* Wih0 = (const float*)d_in[10];
    const float* Whh0 = (const float*)d_in[11];
    const float* bih0 = (const float*)d_in[12];
    const float* bhh0 = (const float*)d_in[13];
    const float* Wih1 = (const float*)d_in[14];
    const float* Whh1 = (const float*)d_in[15];
    const float* bih1 = (const float*)d_in[16];
    const float* bhh1 = (const float*)d_in[17];
    const float* lng  = (const float*)d_in[18];
    const float* lnb  = (const float*)d_in[19];
    const float* hw1  = (const float*)d_in[20];
    const float* hb1  = (const float*)d_in[21];
    const float* hw2  = (const float*)d_in[22];
    const float* hb2  = (const float*)d_in[23];
    float* outp = (float*)d_out;

    f16* xbuf = (f16*)d_ws;                                  // (T,B,H) f16 = 128 MB
    float* hfin = (float*)((char*)d_ws + (size_t)134217728); // 512KB

    conv_k<<<dim3(8192), dim3(512), 0, stream>>>(
        src, w0, b0, w1, b1, w2, b2, w3, b3, pos, xbuf);
    lstm_dual_k<<<dim3(256), dim3(256), 0, stream>>>(
        xbuf, Wih0, Whh0, bih0, bhh0, Wih1, Whh1, bih1, bhh1, hfin);
    head_k<<<dim3(256), dim3(256), 0, stream>>>(
        hfin, lng, lnb, hw1, hb1, hw2, hb2, outp);
}